// Round 1
// baseline (370.366 us; speedup 1.0000x reference)
//
#include <hip/hip_runtime.h>
#include <math.h>

#define S      512
#define BATCH  32
#define TS     64            // tile size = wave size
#define NT     (S / TS)      // 8 tile rows/cols
#define NPH    (2 * NT - 1)  // 15 phases
#define NGRP   256           // diagonal groups of 4: p in [0,1023) -> p>>2 in [0,256)
#define LDSP   68
#define INFF   __builtin_huge_valf()

// wave-wide shift-up-by-1 via DPP wave_shr:1 (VALU latency, no DS pipe).
// lane i gets src[i-1]; lane 0 gets old[0] (bound_ctrl=false keeps old).
__device__ __forceinline__ float dpp_shr1(float src, float old) {
    return __int_as_float(__builtin_amdgcn_update_dpp(
        __float_as_int(old), __float_as_int(src), 0x138, 0xf, 0xf, false));
}

// full-wave rotate: lane i gets src[(i-1)&63] (lane 0 <- lane 63).
__device__ __forceinline__ float dpp_ror1(float src) {
    return __int_as_float(__builtin_amdgcn_update_dpp(
        0, __float_as_int(src), 0x13C, 0xf, 0xf, false));
}

__device__ __forceinline__ float lane_bcast(float v, int l) {
    return __int_as_float(__builtin_amdgcn_readlane(__float_as_int(v), l));
}

// ---------------------------------------------------------------------------
// Kernel 1: D[b,i,j] = |x_i|^2 + |y_j|^2 - 2<x_i,y_j>, stored in 4-wide
// diagonal groups:  ws[b][p>>2][i][p&3]  with p = i + j.
// v2: stage the tile in LDS in diagonal layout (reusing the XsT/YsT memory),
// then store float4 (one group, 4 diagonals) per lane, coalesced across i.
// ---------------------------------------------------------------------------
__global__ __launch_bounds__(256) void pairdist_kernel(
    const float* __restrict__ X, const float* __restrict__ Y,
    float* __restrict__ Dd)
{
    const int b   = blockIdx.z;
    const int i0  = blockIdx.y * 64;
    const int j0  = blockIdx.x * 64;
    const int tid = threadIdx.x;

    __shared__ float smem[64 * LDSP * 2];   // XsT|YsT first, diag tile later
    __shared__ float x2s[64], y2s[64];
    float* XsT = smem;                // [k][i] stride LDSP
    float* YsT = smem + 64 * LDSP;    // [k][j] stride LDSP

    const float* Xb = X + ((size_t)b * S + i0) * 64;
    const float* Yb = Y + ((size_t)b * S + j0) * 64;

#pragma unroll
    for (int c = 0; c < 4; ++c) {
        int idx = c * 1024 + tid * 4;
        int row = idx >> 6;
        int k   = idx & 63;
        float4 vx = *(const float4*)(Xb + (size_t)row * 64 + k);
        float4 vy = *(const float4*)(Yb + (size_t)row * 64 + k);
        XsT[(k + 0) * LDSP + row] = vx.x; XsT[(k + 1) * LDSP + row] = vx.y;
        XsT[(k + 2) * LDSP + row] = vx.z; XsT[(k + 3) * LDSP + row] = vx.w;
        YsT[(k + 0) * LDSP + row] = vy.x; YsT[(k + 1) * LDSP + row] = vy.y;
        YsT[(k + 2) * LDSP + row] = vy.z; YsT[(k + 3) * LDSP + row] = vy.w;
    }
    __syncthreads();

    if (tid < 64) {
        float s = 0.f;
#pragma unroll 8
        for (int k = 0; k < 64; ++k) { float v = XsT[k * LDSP + tid]; s = fmaf(v, v, s); }
        x2s[tid] = s;
    } else if (tid < 128) {
        int r = tid - 64;
        float s = 0.f;
#pragma unroll 8
        for (int k = 0; k < 64; ++k) { float v = YsT[k * LDSP + r]; s = fmaf(v, v, s); }
        y2s[r] = s;
    }
    __syncthreads();

    const int tx = tid & 15;
    const int ty = tid >> 4;
    float acc[4][4] = {};
#pragma unroll 4
    for (int k = 0; k < 64; ++k) {
        float4 a  = *(const float4*)&XsT[k * LDSP + ty * 4];
        float4 bb = *(const float4*)&YsT[k * LDSP + tx * 4];
        float av[4] = {a.x, a.y, a.z, a.w};
        float bv[4] = {bb.x, bb.y, bb.z, bb.w};
#pragma unroll
        for (int r = 0; r < 4; ++r)
#pragma unroll
            for (int c = 0; c < 4; ++c)
                acc[r][c] = fmaf(av[r], bv[c], acc[r][c]);
    }

    float xr[4], yc[4];
#pragma unroll
    for (int r = 0; r < 4; ++r) xr[r] = x2s[ty * 4 + r];
#pragma unroll
    for (int c = 0; c < 4; ++c) yc[c] = y2s[tx * 4 + c];

    float vout[4][4];
#pragma unroll
    for (int r = 0; r < 4; ++r)
#pragma unroll
        for (int c = 0; c < 4; ++c)
            vout[r][c] = xr[r] + yc[c] - 2.0f * acc[r][c];   // same expr/order as before

    __syncthreads();   // everyone done reading XsT/YsT -> smem becomes diag tile

    // diag layout: [il][p_local], row stride 127 (p_local = il + jl in [0,127))
    // write addr = il*127 + (il+jl) = il*128 + jl.
    // c rotated by (tx+ty) so a wave's 64 simultaneous dword writes spread over
    // all 32 banks (2-way max) instead of 8-way.
    float* diag = smem;
#pragma unroll
    for (int r = 0; r < 4; ++r) {
        int il = ty * 4 + r;
#pragma unroll
        for (int cc = 0; cc < 4; ++cc) {
            int c   = (cc + tx + ty) & 3;
            float v = vout[r][0];
            v = (c == 1) ? vout[r][1] : v;
            v = (c == 2) ? vout[r][2] : v;
            v = (c == 3) ? vout[r][3] : v;
            int jl = tx * 4 + c;
            diag[il * 128 + jl] = v;
        }
    }
    __syncthreads();

    // store phase: wave w handles groups gl = w + 4t; lane = row il.
    // full groups -> float4 store, contiguous across lanes (coalesced 16B/lane);
    // tile-edge groups -> per-component dword stores.
    const int w     = tid >> 6;
    const int il    = tid & 63;
    const int gbase = (i0 + j0) >> 2;
    float* dstB = Dd + (size_t)b * (NGRP * S * 4);
#pragma unroll
    for (int t = 0; t < 8; ++t) {
        int gl   = w + 4 * t;
        int joff = 4 * gl - il;               // j_local of component k=0
        float c0 = diag[il * 127 + 4 * gl + 0];
        float c1 = diag[il * 127 + 4 * gl + 1];
        float c2 = diag[il * 127 + 4 * gl + 2];
        float c3 = diag[il * 127 + 4 * gl + 3];
        size_t base = ((size_t)(gbase + gl) * S + (i0 + il)) * 4;
        if (joff >= 0 && joff <= 60) {
            float4 v; v.x = c0; v.y = c1; v.z = c2; v.w = c3;
            *(float4*)(dstB + base) = v;
        } else {
            if ((unsigned)(joff + 0) <= 63u) dstB[base + 0] = c0;
            if ((unsigned)(joff + 1) <= 63u) dstB[base + 1] = c1;
            if ((unsigned)(joff + 2) <= 63u) dstB[base + 2] = c2;
            if ((unsigned)(joff + 3) <= 63u) dstB[base + 3] = c3;
        }
    }
}

// ---------------------------------------------------------------------------
// Kernel 2: tiled wavefront soft-DTW DP, DPP edition v2.
// One block/batch; wave I owns tile-row I; lane l owns row 64I+l.
// Changes vs v1 (all data-movement only; FP graph identical -> bit-exact):
//  - top row kept reversed in a register (trev[l] = T[63-l]); a tshift copy is
//    wave_ror:1'ed each step so lane 0 always holds T[s] for the DPP old
//    operand. No per-step readlane/s_min/v_mov.
//  - bottom row collected by blend(lane63) + wave_ror:1 into tacc; insertions
//    at steps 63..126 land exactly in reversed layout. No per-step exec-masked
//    ds_write; one ds_write per lane at phase end.
//  - active-lane mask maintained on the SCALAR pipe (s_lshl_b64/s_or) and
//    applied with a single v_cndmask (inline asm) -> 2 fewer VALU/step.
//  - dead step s=127 dropped (no active lanes).
//  - prefetch queue deepened 4 -> 8 float4 (32-step lookahead).
// ---------------------------------------------------------------------------
__global__ __launch_bounds__(512) void softdtw_dp_dpp(
    const float* __restrict__ Dd, float* __restrict__ out)
{
    const int b    = blockIdx.x;
    const int tid  = threadIdx.x;
    const int I    = tid >> 6;   // wave id = tile row
    const int lane = tid & 63;

    __shared__ float Btop[2][NT + 1][TS];
    if (tid < 128) Btop[tid >> 6][NT][tid & 63] = INFF;  // virtual INF top row
    __syncthreads();

    const float4* __restrict__ Dbat =
        (const float4*)(Dd + (size_t)b * (NGRP * S * 4));

    const bool is63 = (lane == 63);
    float r_cur  = INFF;                     // carries left boundary between phases
    float corner = (I == 0) ? 0.0f : INFF;   // R[64I-1][64J-1] seed for J==0

    for (int d = 0; d < NPH; ++d) {
        const int J = d - I;
        if (0 <= J && J < NT) {
            const int prow = (I == 0) ? NT : (I - 1);
            float trev   = Btop[(d + 1) & 1][prow][lane];  // trev[l] = T[63-l]
            float tshift = dpp_ror1(trev);                 // lane0 = T[0]
            float tacc   = 0.0f;                           // bottom-row collector
            unsigned long long am = 0ull;                  // active-lane mask

            // lane's D stream: group 16d+u, row 64I+lane, components p&3
            const float4* __restrict__ qp =
                Dbat + (size_t)(16 * d) * S + (TS * I + lane);
            float4 qbuf[8];
#pragma unroll
            for (int u = 0; u < 8; ++u) qbuf[u] = qp[(size_t)u * S];

            // seed dd: lane0 <- corner, lane i <- r_cur[i-1] (phase-entry vals)
            float up_prev = dpp_shr1(r_cur, corner);

#define DP_STEP(QC, OR1)                                                 \
            {                                                            \
                float up = dpp_shr1(r_cur, tshift);   /* lane0 <- T[s] */\
                tshift   = dpp_ror1(tshift);                             \
                float dd = up_prev;                                      \
                float lf = r_cur;                                        \
                float mn = fminf(up, fminf(dd, lf));                     \
                float e  = __expf(mn - dd) + __expf(mn - up)             \
                         + __expf(mn - lf);                              \
                float val = (QC) + (mn - __logf(e));                     \
                am = (OR1) ? ((am << 1) | 1ull) : (am << 1);             \
                asm("v_cndmask_b32 %0, %1, %2, %3"                       \
                    : "=v"(r_cur) : "v"(r_cur), "v"(val), "s"(am));      \
                tacc    = dpp_ror1(is63 ? r_cur : tacc);                 \
                up_prev = up;                                            \
            }

#pragma unroll 4
            for (int u = 0; u < 16; ++u) {        // s = 0..63 (mask widens)
                float4 q = qbuf[u & 7];
                qbuf[u & 7] = qp[(size_t)(u + 8) * S];   // rows 8..23
                DP_STEP(q.x, true) DP_STEP(q.y, true)
                DP_STEP(q.z, true) DP_STEP(q.w, true)
            }
#pragma unroll 4
            for (int u = 16; u < 24; ++u) {       // s = 64..95 (mask shrinks)
                float4 q = qbuf[u & 7];
                qbuf[u & 7] = qp[(size_t)(u + 8) * S];   // rows 24..31
                DP_STEP(q.x, false) DP_STEP(q.y, false)
                DP_STEP(q.z, false) DP_STEP(q.w, false)
            }
#pragma unroll 4
            for (int u = 24; u < 31; ++u) {       // s = 96..123, queue drains
                float4 q = qbuf[u & 7];
                DP_STEP(q.x, false) DP_STEP(q.y, false)
                DP_STEP(q.z, false) DP_STEP(q.w, false)
            }
            {                                      // u = 31: s = 124..126 only
                float4 q = qbuf[7];
                DP_STEP(q.x, false) DP_STEP(q.y, false) DP_STEP(q.z, false)
            }
#undef DP_STEP

            Btop[d & 1][I][lane] = tacc;           // reversed bottom row -> next wave
            corner = lane_bcast(trev, 0);          // T[63] -> next tile's corner
        }
        __syncthreads();
    }

    if (tid == S - 1) out[b] = r_cur;   // R[511][511]
}

// ---------------------------------------------------------------------------
extern "C" void kernel_launch(void* const* d_in, const int* in_sizes, int n_in,
                              void* d_out, int out_size, void* d_ws, size_t ws_size,
                              hipStream_t stream)
{
    const float* X = (const float*)d_in[0];
    const float* Y = (const float*)d_in[1];
    float* out = (float*)d_out;
    float* Dd  = (float*)d_ws;   // 32 * 256*512*4 floats = 64 MiB

    dim3 g1(S / 64, S / 64, BATCH);
    pairdist_kernel<<<g1, 256, 0, stream>>>(X, Y, Dd);

    softdtw_dp_dpp<<<BATCH, 512, 0, stream>>>(Dd, out);
}

// Round 3
// 324.687 us; speedup vs baseline: 1.1407x; 1.1407x over previous
//
#include <hip/hip_runtime.h>
#include <math.h>

#define S      512
#define BATCH  32
#define TS     64            // tile size = wave size
#define NT     (S / TS)      // 8 tile rows/cols
#define NPH    (2 * NT - 1)  // 15 phases
#define NGRP   256           // diagonal groups of 4: p in [0,1023) -> p>>2 in [0,256)
#define LDSP   68
#define INFF   __builtin_huge_valf()

// wave-wide shift-up-by-1 via DPP wave_shr:1 (VALU latency, no DS pipe).
// lane i gets src[i-1]; lane 0 gets old[0] (bound_ctrl=false keeps old).
__device__ __forceinline__ float dpp_shr1(float src, float old) {
    return __int_as_float(__builtin_amdgcn_update_dpp(
        __float_as_int(old), __float_as_int(src), 0x138, 0xf, 0xf, false));
}

// full-wave rotate: lane i gets src[(i-1)&63] (lane 0 <- lane 63).
__device__ __forceinline__ float dpp_ror1(float src) {
    return __int_as_float(__builtin_amdgcn_update_dpp(
        0, __float_as_int(src), 0x13C, 0xf, 0xf, false));
}

__device__ __forceinline__ float lane_bcast(float v, int l) {
    return __int_as_float(__builtin_amdgcn_readlane(__float_as_int(v), l));
}

// ---------------------------------------------------------------------------
// Kernel 1: D[b,i,j] = |x_i|^2 + |y_j|^2 - 2<x_i,y_j>, stored in 4-wide
// diagonal groups:  ws[b][p>>2][i][p&3]  with p = i + j.
// Stages the tile in LDS in diagonal layout (reusing the XsT/YsT memory),
// then stores float4 (one group, 4 diagonals) per lane, coalesced across i.
// ---------------------------------------------------------------------------
__global__ __launch_bounds__(256) void pairdist_kernel(
    const float* __restrict__ X, const float* __restrict__ Y,
    float* __restrict__ Dd)
{
    const int b   = blockIdx.z;
    const int i0  = blockIdx.y * 64;
    const int j0  = blockIdx.x * 64;
    const int tid = threadIdx.x;

    __shared__ float smem[64 * LDSP * 2];   // XsT|YsT first, diag tile later
    __shared__ float x2s[64], y2s[64];
    float* XsT = smem;                // [k][i] stride LDSP
    float* YsT = smem + 64 * LDSP;    // [k][j] stride LDSP

    const float* Xb = X + ((size_t)b * S + i0) * 64;
    const float* Yb = Y + ((size_t)b * S + j0) * 64;

#pragma unroll
    for (int c = 0; c < 4; ++c) {
        int idx = c * 1024 + tid * 4;
        int row = idx >> 6;
        int k   = idx & 63;
        float4 vx = *(const float4*)(Xb + (size_t)row * 64 + k);
        float4 vy = *(const float4*)(Yb + (size_t)row * 64 + k);
        XsT[(k + 0) * LDSP + row] = vx.x; XsT[(k + 1) * LDSP + row] = vx.y;
        XsT[(k + 2) * LDSP + row] = vx.z; XsT[(k + 3) * LDSP + row] = vx.w;
        YsT[(k + 0) * LDSP + row] = vy.x; YsT[(k + 1) * LDSP + row] = vy.y;
        YsT[(k + 2) * LDSP + row] = vy.z; YsT[(k + 3) * LDSP + row] = vy.w;
    }
    __syncthreads();

    if (tid < 64) {
        float s = 0.f;
#pragma unroll 8
        for (int k = 0; k < 64; ++k) { float v = XsT[k * LDSP + tid]; s = fmaf(v, v, s); }
        x2s[tid] = s;
    } else if (tid < 128) {
        int r = tid - 64;
        float s = 0.f;
#pragma unroll 8
        for (int k = 0; k < 64; ++k) { float v = YsT[k * LDSP + r]; s = fmaf(v, v, s); }
        y2s[r] = s;
    }
    __syncthreads();

    const int tx = tid & 15;
    const int ty = tid >> 4;
    float acc[4][4] = {};
#pragma unroll 4
    for (int k = 0; k < 64; ++k) {
        float4 a  = *(const float4*)&XsT[k * LDSP + ty * 4];
        float4 bb = *(const float4*)&YsT[k * LDSP + tx * 4];
        float av[4] = {a.x, a.y, a.z, a.w};
        float bv[4] = {bb.x, bb.y, bb.z, bb.w};
#pragma unroll
        for (int r = 0; r < 4; ++r)
#pragma unroll
            for (int c = 0; c < 4; ++c)
                acc[r][c] = fmaf(av[r], bv[c], acc[r][c]);
    }

    float xr[4], yc[4];
#pragma unroll
    for (int r = 0; r < 4; ++r) xr[r] = x2s[ty * 4 + r];
#pragma unroll
    for (int c = 0; c < 4; ++c) yc[c] = y2s[tx * 4 + c];

    float vout[4][4];
#pragma unroll
    for (int r = 0; r < 4; ++r)
#pragma unroll
        for (int c = 0; c < 4; ++c)
            vout[r][c] = xr[r] + yc[c] - 2.0f * acc[r][c];   // same expr/order as before

    __syncthreads();   // everyone done reading XsT/YsT -> smem becomes diag tile

    // diag layout: [il][p_local], row stride 127 (p_local = il + jl in [0,127))
    // write addr = il*127 + (il+jl) = il*128 + jl.
    // c rotated by (tx+ty) so a wave's 64 simultaneous dword writes spread over
    // all 32 banks (2-way max) instead of 8-way.
    float* diag = smem;
#pragma unroll
    for (int r = 0; r < 4; ++r) {
        int il = ty * 4 + r;
#pragma unroll
        for (int cc = 0; cc < 4; ++cc) {
            int c   = (cc + tx + ty) & 3;
            float v = vout[r][0];
            v = (c == 1) ? vout[r][1] : v;
            v = (c == 2) ? vout[r][2] : v;
            v = (c == 3) ? vout[r][3] : v;
            int jl = tx * 4 + c;
            diag[il * 128 + jl] = v;
        }
    }
    __syncthreads();

    // store phase: wave w handles groups gl = w + 4t; lane = row il.
    // full groups -> float4 store, contiguous across lanes (coalesced 16B/lane);
    // tile-edge groups -> per-component dword stores.
    const int w     = tid >> 6;
    const int il    = tid & 63;
    const int gbase = (i0 + j0) >> 2;
    float* dstB = Dd + (size_t)b * (NGRP * S * 4);
#pragma unroll
    for (int t = 0; t < 8; ++t) {
        int gl   = w + 4 * t;
        int joff = 4 * gl - il;               // j_local of component k=0
        float c0 = diag[il * 127 + 4 * gl + 0];
        float c1 = diag[il * 127 + 4 * gl + 1];
        float c2 = diag[il * 127 + 4 * gl + 2];
        float c3 = diag[il * 127 + 4 * gl + 3];
        size_t base = ((size_t)(gbase + gl) * S + (i0 + il)) * 4;
        if (joff >= 0 && joff <= 60) {
            float4 v; v.x = c0; v.y = c1; v.z = c2; v.w = c3;
            *(float4*)(dstB + base) = v;
        } else {
            if ((unsigned)(joff + 0) <= 63u) dstB[base + 0] = c0;
            if ((unsigned)(joff + 1) <= 63u) dstB[base + 1] = c1;
            if ((unsigned)(joff + 2) <= 63u) dstB[base + 2] = c2;
            if ((unsigned)(joff + 3) <= 63u) dstB[base + 3] = c3;
        }
    }
}

// ---------------------------------------------------------------------------
// Kernel 2: tiled wavefront soft-DTW DP, DPP edition v3.
// One block/batch; wave I owns tile-row I; lane l owns row 64I+l.
// vs v2 (which spilled qbuf + materialized 127 SGPR-pair constants):
//  - prefetch queue back to 4 float4 (16 VGPRs, no scratch; WRITE_SIZE->~0)
//  - predication via plain (lane <= s) / (lane >= s-63) compares: s is a
//    compile-time inline constant -> v_cmp + v_cndmask, no SGPR immediates
//  - tacc blend+ror only for s >= 63 (inserts land at lanes 63..0 exactly);
//    tshift ror only for s <= 62 (lane0 past T[63] is never consumed)
//  - dead step s=127 still dropped
// FP graph per cell identical to v1/v2 -> bit-exact (absmax 0.0).
// ---------------------------------------------------------------------------
__global__ __launch_bounds__(512) void softdtw_dp_dpp(
    const float* __restrict__ Dd, float* __restrict__ out)
{
    const int b    = blockIdx.x;
    const int tid  = threadIdx.x;
    const int I    = tid >> 6;   // wave id = tile row
    const int lane = tid & 63;

    __shared__ float Btop[2][NT + 1][TS];
    if (tid < 128) Btop[tid >> 6][NT][tid & 63] = INFF;  // virtual INF top row
    __syncthreads();

    const float4* __restrict__ Dbat =
        (const float4*)(Dd + (size_t)b * (NGRP * S * 4));

    const bool is63 = (lane == 63);
    float r_cur  = INFF;                     // carries left boundary between phases
    float corner = (I == 0) ? 0.0f : INFF;   // R[64I-1][64J-1] seed for J==0

    for (int d = 0; d < NPH; ++d) {
        const int J = d - I;
        if (0 <= J && J < NT) {
            const int prow = (I == 0) ? NT : (I - 1);
            float trev   = Btop[(d + 1) & 1][prow][lane];  // trev[l] = T[63-l]
            float tshift = dpp_ror1(trev);                 // lane0 = T[0]
            float tacc   = 0.0f;                           // bottom-row collector

            // lane's D stream: group 16d+u, row 64I+lane, components p&3
            const float4* __restrict__ qp =
                Dbat + (size_t)(16 * d) * S + (TS * I + lane);
            float4 qbuf[4];
#pragma unroll
            for (int u = 0; u < 4; ++u) qbuf[u] = qp[(size_t)u * S];

            // seed dd: lane0 <- corner, lane i <- r_cur[i-1] (phase-entry vals)
            float up_prev = dpp_shr1(r_cur, corner);

            // ACT must be a compile-time-constant-vs-lane compare.
            // ROR / TAC are compile-time bools -> folded.
#define DP_STEP(QC, ACT, ROR, TAC)                                       \
            {                                                            \
                float up = dpp_shr1(r_cur, tshift);   /* lane0 <- T[s] */\
                if (ROR) tshift = dpp_ror1(tshift);                      \
                float dd = up_prev;                                      \
                float lf = r_cur;                                        \
                float mn = fminf(up, fminf(dd, lf));                     \
                float e  = __expf(mn - dd) + __expf(mn - up)             \
                         + __expf(mn - lf);                              \
                float val = (QC) + (mn - __logf(e));                     \
                r_cur = (ACT) ? val : r_cur;                             \
                if (TAC) tacc = dpp_ror1(is63 ? r_cur : tacc);           \
                up_prev = up;                                            \
            }

            // first half: u = 0..15, s = 4u+j in [0,63]; act = (lane <= s)
#pragma unroll
            for (int u = 0; u < 16; ++u) {
                float4 q = qbuf[u & 3];
                qbuf[u & 3] = qp[(size_t)(u + 4) * S];    // rows 4..19
                const int s0 = 4 * u;
                DP_STEP(q.x, lane <= s0 + 0, true, false)
                DP_STEP(q.y, lane <= s0 + 1, true, false)
                DP_STEP(q.z, lane <= s0 + 2, true, false)
                DP_STEP(q.w, lane <= s0 + 3, (s0 + 3) < 63, (s0 + 3) == 63)
            }
            // second half: u = 16..31, s in [64,126]; act = (lane >= s-63)
#pragma unroll
            for (int u = 16; u < 32; ++u) {
                float4 q = qbuf[u & 3];
                if (u + 4 < 32) qbuf[u & 3] = qp[(size_t)(u + 4) * S];
                const int s0 = 4 * u;
                DP_STEP(q.x, lane >= s0 + 0 - 63, false, true)
                DP_STEP(q.y, lane >= s0 + 1 - 63, false, true)
                DP_STEP(q.z, lane >= s0 + 2 - 63, false, true)
                if (u != 31)
                    DP_STEP(q.w, lane >= s0 + 3 - 63, false, true)
            }
#undef DP_STEP

            Btop[d & 1][I][lane] = tacc;           // reversed bottom row -> next wave
            corner = lane_bcast(trev, 0);          // T[63] -> next tile's corner
        }
        __syncthreads();
    }

    if (tid == S - 1) out[b] = r_cur;   // R[511][511]
}

// ---------------------------------------------------------------------------
extern "C" void kernel_launch(void* const* d_in, const int* in_sizes, int n_in,
                              void* d_out, int out_size, void* d_ws, size_t ws_size,
                              hipStream_t stream)
{
    const float* X = (const float*)d_in[0];
    const float* Y = (const float*)d_in[1];
    float* out = (float*)d_out;
    float* Dd  = (float*)d_ws;   // 32 * 256*512*4 floats = 64 MiB

    dim3 g1(S / 64, S / 64, BATCH);
    pairdist_kernel<<<g1, 256, 0, stream>>>(X, Y, Dd);

    softdtw_dp_dpp<<<BATCH, 512, 0, stream>>>(Dd, out);
}

// Round 4
// 303.218 us; speedup vs baseline: 1.2215x; 1.0708x over previous
//
#include <hip/hip_runtime.h>
#include <math.h>

#define S      512
#define BATCH  32
#define NGRP   256           // diagonal groups of 4: p in [0,1023) -> p>>2 in [0,256)
#define LDSP   68
#define INFF   __builtin_huge_valf()

// wave-wide shift-up-by-1 via DPP wave_shr:1 (VALU, no DS pipe).
// lane i gets src[i-1]; lane 0 gets old's lane-0 value (bound_ctrl=false).
__device__ __forceinline__ float dpp_shr1(float src, float old) {
    return __int_as_float(__builtin_amdgcn_update_dpp(
        __float_as_int(old), __float_as_int(src), 0x138, 0xf, 0xf, false));
}

// full-wave rotate: lane i gets src[(i-1)&63] (lane 0 <- lane 63).
__device__ __forceinline__ float dpp_ror1(float src) {
    return __int_as_float(__builtin_amdgcn_update_dpp(
        0, __float_as_int(src), 0x13C, 0xf, 0xf, false));
}

__device__ __forceinline__ float lane_bcast(float v, int l) {
    return __int_as_float(__builtin_amdgcn_readlane(__float_as_int(v), l));
}

// ---------------------------------------------------------------------------
// Kernel 1: D[b,i,j] = |x_i|^2 + |y_j|^2 - 2<x_i,y_j>, stored in 4-wide
// diagonal groups:  ws[b][p>>2][i][p&3]  with p = i + j.  (unchanged)
// ---------------------------------------------------------------------------
__global__ __launch_bounds__(256) void pairdist_kernel(
    const float* __restrict__ X, const float* __restrict__ Y,
    float* __restrict__ Dd)
{
    const int b   = blockIdx.z;
    const int i0  = blockIdx.y * 64;
    const int j0  = blockIdx.x * 64;
    const int tid = threadIdx.x;

    __shared__ float smem[64 * LDSP * 2];
    __shared__ float x2s[64], y2s[64];
    float* XsT = smem;
    float* YsT = smem + 64 * LDSP;

    const float* Xb = X + ((size_t)b * S + i0) * 64;
    const float* Yb = Y + ((size_t)b * S + j0) * 64;

#pragma unroll
    for (int c = 0; c < 4; ++c) {
        int idx = c * 1024 + tid * 4;
        int row = idx >> 6;
        int k   = idx & 63;
        float4 vx = *(const float4*)(Xb + (size_t)row * 64 + k);
        float4 vy = *(const float4*)(Yb + (size_t)row * 64 + k);
        XsT[(k + 0) * LDSP + row] = vx.x; XsT[(k + 1) * LDSP + row] = vx.y;
        XsT[(k + 2) * LDSP + row] = vx.z; XsT[(k + 3) * LDSP + row] = vx.w;
        YsT[(k + 0) * LDSP + row] = vy.x; YsT[(k + 1) * LDSP + row] = vy.y;
        YsT[(k + 2) * LDSP + row] = vy.z; YsT[(k + 3) * LDSP + row] = vy.w;
    }
    __syncthreads();

    if (tid < 64) {
        float s = 0.f;
#pragma unroll 8
        for (int k = 0; k < 64; ++k) { float v = XsT[k * LDSP + tid]; s = fmaf(v, v, s); }
        x2s[tid] = s;
    } else if (tid < 128) {
        int r = tid - 64;
        float s = 0.f;
#pragma unroll 8
        for (int k = 0; k < 64; ++k) { float v = YsT[k * LDSP + r]; s = fmaf(v, v, s); }
        y2s[r] = s;
    }
    __syncthreads();

    const int tx = tid & 15;
    const int ty = tid >> 4;
    float acc[4][4] = {};
#pragma unroll 4
    for (int k = 0; k < 64; ++k) {
        float4 a  = *(const float4*)&XsT[k * LDSP + ty * 4];
        float4 bb = *(const float4*)&YsT[k * LDSP + tx * 4];
        float av[4] = {a.x, a.y, a.z, a.w};
        float bv[4] = {bb.x, bb.y, bb.z, bb.w};
#pragma unroll
        for (int r = 0; r < 4; ++r)
#pragma unroll
            for (int c = 0; c < 4; ++c)
                acc[r][c] = fmaf(av[r], bv[c], acc[r][c]);
    }

    float xr[4], yc[4];
#pragma unroll
    for (int r = 0; r < 4; ++r) xr[r] = x2s[ty * 4 + r];
#pragma unroll
    for (int c = 0; c < 4; ++c) yc[c] = y2s[tx * 4 + c];

    float vout[4][4];
#pragma unroll
    for (int r = 0; r < 4; ++r)
#pragma unroll
        for (int c = 0; c < 4; ++c)
            vout[r][c] = xr[r] + yc[c] - 2.0f * acc[r][c];

    __syncthreads();

    float* diag = smem;
#pragma unroll
    for (int r = 0; r < 4; ++r) {
        int il = ty * 4 + r;
#pragma unroll
        for (int cc = 0; cc < 4; ++cc) {
            int c   = (cc + tx + ty) & 3;
            float v = vout[r][0];
            v = (c == 1) ? vout[r][1] : v;
            v = (c == 2) ? vout[r][2] : v;
            v = (c == 3) ? vout[r][3] : v;
            int jl = tx * 4 + c;
            diag[il * 128 + jl] = v;
        }
    }
    __syncthreads();

    const int w     = tid >> 6;
    const int il    = tid & 63;
    const int gbase = (i0 + j0) >> 2;
    float* dstB = Dd + (size_t)b * (NGRP * S * 4);
#pragma unroll
    for (int t = 0; t < 8; ++t) {
        int gl   = w + 4 * t;
        int joff = 4 * gl - il;
        float c0 = diag[il * 127 + 4 * gl + 0];
        float c1 = diag[il * 127 + 4 * gl + 1];
        float c2 = diag[il * 127 + 4 * gl + 2];
        float c3 = diag[il * 127 + 4 * gl + 3];
        size_t base = ((size_t)(gbase + gl) * S + (i0 + il)) * 4;
        if (joff >= 0 && joff <= 60) {
            float4 v; v.x = c0; v.y = c1; v.z = c2; v.w = c3;
            *(float4*)(dstB + base) = v;
        } else {
            if ((unsigned)(joff + 0) <= 63u) dstB[base + 0] = c0;
            if ((unsigned)(joff + 1) <= 63u) dstB[base + 1] = c1;
            if ((unsigned)(joff + 2) <= 63u) dstB[base + 2] = c2;
            if ((unsigned)(joff + 3) <= 63u) dstB[base + 3] = c3;
        }
    }
}

// ---------------------------------------------------------------------------
// Kernel 2 (v4): staggered-wave soft-DTW DP.
// 4 waves/batch (1 per SIMD). Wave w owns rows [128w,128w+128); lane l owns
// rows i0=128w+2l, i1=i0+1 (2 cells/step ILP). Waves are pipelined with a
// 64-diagonal stagger: in super-step n, wave w processes global diagonals
// p = (n-w)*64 + k, k=0..63. Boundary row (wave w's row 128w+127) streams to
// wave w+1 through an LDS ring (double-buffered, one barrier per super-step).
// Wall steps: 1023 + 3*64 ~ 1216 (vs 1905 in the tiled version).
// Banks: X holds even diagonals, Y odd. Step p reads cur=diag p-1, prv=p-2,
// writes prv bank in place (SSA; dd reads the old value first).
// Activation predication (i <= p) only in the first two super-steps of a
// wave's window; past-end (j>511) cells compute garbage that provably never
// reaches a valid cell (read-before-write order + bank parity).
// Per-cell FP expression identical to v1-v3 -> bit-exact.
// ---------------------------------------------------------------------------
__global__ __launch_bounds__(256) void softdtw_dp_stag(
    const float* __restrict__ Dd, float* __restrict__ out)
{
    const int b    = blockIdx.x;
    const int tid  = threadIdx.x;
    const int w    = tid >> 6;      // wave id 0..3
    const int lane = tid & 63;

    __shared__ float ring[3][2][64];   // boundary stream blocks (reversed)
    __shared__ float extraS[3][2];     // S(p0-1) companion value

    const float4* __restrict__ Dbat =
        (const float4*)(Dd + (size_t)b * (NGRP * S * 4));

    const int  i0   = 128 * w + 2 * lane;
    const bool is63 = (lane == 63);

    float X0 = INFF, X1 = INFF, Y0 = INFF, Y1 = INFF;
    float up_prev = INFF, tshift = INFF, tacc = 0.0f, last_prev = INFF;
    float4 Qa[4], Qb[4];
    int qg = 0;    // rolling D group pointer (group consumed by current iter)

    // one DP step: PW=write bank (holds diag p-2, becomes p), CU=cur (p-1)
#define CELLS(PW0, PW1, CU0, CU1, q0c, q1c, PRED, pk)                     \
    {                                                                     \
        float up0 = dpp_shr1(CU1, tshift);  /* lane0 <- stream(p-1) */    \
        tshift = dpp_ror1(tshift);                                        \
        float dd0 = up_prev, lf0 = CU0;                                   \
        float mn0 = fminf(up0, fminf(dd0, lf0));                          \
        float e0  = __expf(mn0 - dd0) + __expf(mn0 - up0)                 \
                  + __expf(mn0 - lf0);                                    \
        float v0  = (q0c) + (mn0 - __logf(e0));                           \
        float up1 = CU0, dd1 = PW0, lf1 = CU1;                            \
        float mn1 = fminf(up1, fminf(dd1, lf1));                          \
        float e1  = __expf(mn1 - dd1) + __expf(mn1 - up1)                 \
                  + __expf(mn1 - lf1);                                    \
        float v1  = (q1c) + (mn1 - __logf(e1));                           \
        if (PRED) {                                                       \
            v0 = (i0 <= (pk)) ? v0 : PW0;                                 \
            v1 = (i0 + 1 <= (pk)) ? v1 : PW1;                             \
        }                                                                 \
        PW0 = v0; PW1 = v1;                                               \
        tacc = dpp_ror1(is63 ? PW1 : tacc);                               \
        up_prev = up0;                                                    \
    }

    // one group-iter = 4 steps (p even at entry: EVEN,ODD,EVEN,ODD banks)
#define GITER(Qi, PRED, pk)                                               \
    {                                                                     \
        float4 qa = Qa[Qi], qb = Qb[Qi];                                  \
        int gq = qg + 4; gq = (gq > 255) ? 255 : gq;                      \
        const float4* qp = Dbat + (size_t)gq * S + i0;                    \
        Qa[Qi] = qp[0]; Qb[Qi] = qp[1];                                   \
        qg += 1;                                                          \
        CELLS(X0, X1, Y0, Y1, qa.x, qb.x, PRED, (pk) + 0)                 \
        CELLS(Y0, Y1, X0, X1, qa.y, qb.y, PRED, (pk) + 1)                 \
        CELLS(X0, X1, Y0, Y1, qa.z, qb.z, PRED, (pk) + 2)                 \
        CELLS(Y0, Y1, X0, X1, qa.w, qb.w, PRED, (pk) + 3)                 \
    }

    for (int n = 0; n < 19; ++n) {
        const int na = n - 3 * w;
        if (0 <= na && na < 10) {
            const int p0 = 128 * w + 64 * na;

            if (na == 0) {
                up_prev = (w == 0) ? 0.0f : INFF;   // corner seed / INF wall
                qg = 32 * w;
#pragma unroll
                for (int i = 0; i < 4; ++i) {
                    const float4* qp = Dbat + (size_t)(qg + i) * S + i0;
                    Qa[i] = qp[0]; Qb[i] = qp[1];
                }
            }

            if (w > 0) {
                float t  = ring[w - 1][(n - 1) & 1][lane];
                float ex = extraS[w - 1][(n - 1) & 1];
                tshift = (lane == 0) ? ex : t;
            } else {
                tshift = INFF;   // R[-1][*] wall for wave 0
            }

            if (na < 2) {
                int pk = p0;
#pragma unroll 1
                for (int it4 = 0; it4 < 4; ++it4) {
                    GITER(0, true, pk)  GITER(1, true, pk + 4)
                    GITER(2, true, pk + 8) GITER(3, true, pk + 12)
                    pk += 16;
                }
            } else {
                int pk = p0;
#pragma unroll 1
                for (int it4 = 0; it4 < 4; ++it4) {
                    GITER(0, false, pk)  GITER(1, false, pk + 4)
                    GITER(2, false, pk + 8) GITER(3, false, pk + 12)
                    pk += 16;
                }
            }

            if (w < 3) {
                ring[w][n & 1][lane] = tacc;            // reversed stream block
                if (lane == 0) extraS[w][n & 1] = last_prev;  // S(block-1 last)
                last_prev = lane_bcast(tacc, 0);        // this block's last
            }
        }
        __syncthreads();
    }
#undef GITER
#undef CELLS

    // R[511][511]: wave 3, lane 63, row 511 = r1, diag 1022 (even -> X bank)
    if (tid == 255) out[b] = X1;
}

// ---------------------------------------------------------------------------
extern "C" void kernel_launch(void* const* d_in, const int* in_sizes, int n_in,
                              void* d_out, int out_size, void* d_ws, size_t ws_size,
                              hipStream_t stream)
{
    const float* X = (const float*)d_in[0];
    const float* Y = (const float*)d_in[1];
    float* out = (float*)d_out;
    float* Dd  = (float*)d_ws;   // 32 * 256*512*4 floats = 64 MiB

    dim3 g1(S / 64, S / 64, BATCH);
    pairdist_kernel<<<g1, 256, 0, stream>>>(X, Y, Dd);

    softdtw_dp_stag<<<BATCH, 256, 0, stream>>>(Dd, out);
}

// Round 5
// 282.645 us; speedup vs baseline: 1.3104x; 1.0728x over previous
//
#include <hip/hip_runtime.h>
#include <math.h>

#define S      512
#define BATCH  32
#define NGRP   256           // diagonal groups of 4: p in [0,1023) -> p>>2 in [0,256)
#define LDSP   68
#define INFF   __builtin_huge_valf()

// wave-wide shift-up-by-1 via DPP wave_shr:1 (VALU, no DS pipe).
// lane i gets src[i-1]; lane 0 gets old's lane-0 value (bound_ctrl=false).
__device__ __forceinline__ float dpp_shr1(float src, float old) {
    return __int_as_float(__builtin_amdgcn_update_dpp(
        __float_as_int(old), __float_as_int(src), 0x138, 0xf, 0xf, false));
}

// full-wave rotate: lane i gets src[(i-1)&63] (lane 0 <- lane 63).
__device__ __forceinline__ float dpp_ror1(float src) {
    return __int_as_float(__builtin_amdgcn_update_dpp(
        0, __float_as_int(src), 0x13C, 0xf, 0xf, false));
}

__device__ __forceinline__ float lane_bcast(float v, int l) {
    return __int_as_float(__builtin_amdgcn_readlane(__float_as_int(v), l));
}

// ---------------------------------------------------------------------------
// Kernel 1: D[b,i,j] = |x_i|^2 + |y_j|^2 - 2<x_i,y_j>, stored in 4-wide
// diagonal groups:  ws[b][p>>2][i][p&3]  with p = i + j.  (unchanged)
// ---------------------------------------------------------------------------
__global__ __launch_bounds__(256) void pairdist_kernel(
    const float* __restrict__ X, const float* __restrict__ Y,
    float* __restrict__ Dd)
{
    const int b   = blockIdx.z;
    const int i0  = blockIdx.y * 64;
    const int j0  = blockIdx.x * 64;
    const int tid = threadIdx.x;

    __shared__ float smem[64 * LDSP * 2];
    __shared__ float x2s[64], y2s[64];
    float* XsT = smem;
    float* YsT = smem + 64 * LDSP;

    const float* Xb = X + ((size_t)b * S + i0) * 64;
    const float* Yb = Y + ((size_t)b * S + j0) * 64;

#pragma unroll
    for (int c = 0; c < 4; ++c) {
        int idx = c * 1024 + tid * 4;
        int row = idx >> 6;
        int k   = idx & 63;
        float4 vx = *(const float4*)(Xb + (size_t)row * 64 + k);
        float4 vy = *(const float4*)(Yb + (size_t)row * 64 + k);
        XsT[(k + 0) * LDSP + row] = vx.x; XsT[(k + 1) * LDSP + row] = vx.y;
        XsT[(k + 2) * LDSP + row] = vx.z; XsT[(k + 3) * LDSP + row] = vx.w;
        YsT[(k + 0) * LDSP + row] = vy.x; YsT[(k + 1) * LDSP + row] = vy.y;
        YsT[(k + 2) * LDSP + row] = vy.z; YsT[(k + 3) * LDSP + row] = vy.w;
    }
    __syncthreads();

    if (tid < 64) {
        float s = 0.f;
#pragma unroll 8
        for (int k = 0; k < 64; ++k) { float v = XsT[k * LDSP + tid]; s = fmaf(v, v, s); }
        x2s[tid] = s;
    } else if (tid < 128) {
        int r = tid - 64;
        float s = 0.f;
#pragma unroll 8
        for (int k = 0; k < 64; ++k) { float v = YsT[k * LDSP + r]; s = fmaf(v, v, s); }
        y2s[r] = s;
    }
    __syncthreads();

    const int tx = tid & 15;
    const int ty = tid >> 4;
    float acc[4][4] = {};
#pragma unroll 4
    for (int k = 0; k < 64; ++k) {
        float4 a  = *(const float4*)&XsT[k * LDSP + ty * 4];
        float4 bb = *(const float4*)&YsT[k * LDSP + tx * 4];
        float av[4] = {a.x, a.y, a.z, a.w};
        float bv[4] = {bb.x, bb.y, bb.z, bb.w};
#pragma unroll
        for (int r = 0; r < 4; ++r)
#pragma unroll
            for (int c = 0; c < 4; ++c)
                acc[r][c] = fmaf(av[r], bv[c], acc[r][c]);
    }

    float xr[4], yc[4];
#pragma unroll
    for (int r = 0; r < 4; ++r) xr[r] = x2s[ty * 4 + r];
#pragma unroll
    for (int c = 0; c < 4; ++c) yc[c] = y2s[tx * 4 + c];

    float vout[4][4];
#pragma unroll
    for (int r = 0; r < 4; ++r)
#pragma unroll
        for (int c = 0; c < 4; ++c)
            vout[r][c] = xr[r] + yc[c] - 2.0f * acc[r][c];

    __syncthreads();

    float* diag = smem;
#pragma unroll
    for (int r = 0; r < 4; ++r) {
        int il = ty * 4 + r;
#pragma unroll
        for (int cc = 0; cc < 4; ++cc) {
            int c   = (cc + tx + ty) & 3;
            float v = vout[r][0];
            v = (c == 1) ? vout[r][1] : v;
            v = (c == 2) ? vout[r][2] : v;
            v = (c == 3) ? vout[r][3] : v;
            int jl = tx * 4 + c;
            diag[il * 128 + jl] = v;
        }
    }
    __syncthreads();

    const int w     = tid >> 6;
    const int il    = tid & 63;
    const int gbase = (i0 + j0) >> 2;
    float* dstB = Dd + (size_t)b * (NGRP * S * 4);
#pragma unroll
    for (int t = 0; t < 8; ++t) {
        int gl   = w + 4 * t;
        int joff = 4 * gl - il;
        float c0 = diag[il * 127 + 4 * gl + 0];
        float c1 = diag[il * 127 + 4 * gl + 1];
        float c2 = diag[il * 127 + 4 * gl + 2];
        float c3 = diag[il * 127 + 4 * gl + 3];
        size_t base = ((size_t)(gbase + gl) * S + (i0 + il)) * 4;
        if (joff >= 0 && joff <= 60) {
            float4 v; v.x = c0; v.y = c1; v.z = c2; v.w = c3;
            *(float4*)(dstB + base) = v;
        } else {
            if ((unsigned)(joff + 0) <= 63u) dstB[base + 0] = c0;
            if ((unsigned)(joff + 1) <= 63u) dstB[base + 1] = c1;
            if ((unsigned)(joff + 2) <= 63u) dstB[base + 2] = c2;
            if ((unsigned)(joff + 3) <= 63u) dstB[base + 3] = c3;
        }
    }
}

// ---------------------------------------------------------------------------
// Kernel 2 (v5): 8-wave staggered soft-DTW DP, 2 pipeline stages per SIMD.
// 512 threads = 8 waves. Wave w works strip = 2*(w&3) + (w>>2), so SIMD s
// (hosting waves s and s+4, hardware round-robin) gets ADJACENT strips 2s,
// 2s+1 whose active windows overlap 7 of 9 super-steps -> the two waves fill
// each other's dependency-stall slots (v4 had 1 wave/SIMD: 70% stall).
// Strip owns rows [64*strip, 64*strip+64), lane l = row 64*strip + l.
// Stagger factor 2: in super-step n, strip does window na = n - 2*strip
// (na in [0,9)), processing diagonals p = 64*strip + 64*na + k, k = 0..63.
// Boundary row (lane 63) streams to strip+1 through the same double-buffered
// reversed ring + extraS protocol verified in v4 (consumer window na reads
// [last of producer window na (extraS), first 63 of window na+1 (ring)]).
// Window 8's stale-ring reads feed only j>511 garbage cells (lane0's valid
// cells need stream diags <= 64s+510, all delivered); garbage stays confined
// to the j>511 region (diagonal propagation preserves j), and the final
// p=1023 garbage step writes the ODD bank while the output (p=1022) lives in
// the EVEN bank. Per-cell FP expression identical to v1-v4 -> bit-exact.
// ---------------------------------------------------------------------------
__global__ __launch_bounds__(512) void softdtw_dp_stag8(
    const float* __restrict__ Dd, float* __restrict__ out)
{
    const int b     = blockIdx.x;
    const int tid   = threadIdx.x;
    const int w     = tid >> 6;
    const int lane  = tid & 63;
    const int strip = 2 * (w & 3) + (w >> 2);   // SIMD-pairing permutation

    __shared__ float ring[7][2][64];   // reversed boundary blocks
    __shared__ float extraS[7][2];     // previous block's last value

    const float4* __restrict__ Dbat =
        (const float4*)(Dd + (size_t)b * (NGRP * S * 4));

    const int  i0   = 64 * strip + lane;     // this lane's row
    const bool is63 = (lane == 63);

    float rE = INFF, rO = INFF;        // even-diag bank, odd-diag bank
    float up_prev = INFF, tshift = INFF, tacc = 0.0f, last_prev = INFF;
    float4 Q[4];
    int qg = 0;                        // group consumed by current GITER

    // one cell: PW = write bank (diag p-2 -> p), CU = other bank (diag p-1)
#define CELL1(PW, CU, qc, PRED, kk)                                      \
    {                                                                    \
        float up = dpp_shr1(CU, tshift);   /* lane0 <- stream(p-1) */    \
        tshift = dpp_ror1(tshift);                                       \
        float dd = up_prev, lf = CU;                                     \
        float mn = fminf(up, fminf(dd, lf));                             \
        float e  = __expf(mn - dd) + __expf(mn - up) + __expf(mn - lf);  \
        float val = (qc) + (mn - __logf(e));                             \
        if (PRED) val = (lane <= (kk)) ? val : PW;                       \
        PW = val;                                                        \
        tacc = dpp_ror1(is63 ? PW : tacc);                               \
        up_prev = up;                                                    \
    }

    // 4 steps = one D group (p0 = multiple of 4 -> parity E,O,E,O static)
#define GITER1(Qi, PRED, kk)                                             \
    {                                                                    \
        float4 q = Q[Qi];                                                \
        int gq = qg + 4; gq = (gq > 255) ? 255 : gq;                     \
        Q[Qi] = *(Dbat + (size_t)gq * S + i0);                           \
        qg += 1;                                                         \
        CELL1(rE, rO, q.x, PRED, (kk) + 0)                               \
        CELL1(rO, rE, q.y, PRED, (kk) + 1)                               \
        CELL1(rE, rO, q.z, PRED, (kk) + 2)                               \
        CELL1(rO, rE, q.w, PRED, (kk) + 3)                               \
    }

    for (int n = 0; n < 23; ++n) {
        const int na = n - 2 * strip;
        if (0 <= na && na < 9) {
            if (na == 0) {                 // strip-run start: seed + queue fill
                up_prev = (strip == 0) ? 0.0f : INFF;   // corner / INF wall
                qg = 16 * strip;
#pragma unroll
                for (int i = 0; i < 4; ++i)
                    Q[i] = *(Dbat + (size_t)(qg + i) * S + i0);
            }
            if (strip > 0) {               // load stream block for this window
                float t  = ring[strip - 1][(n - 1) & 1][lane];
                float ex = extraS[strip - 1][(n - 1) & 1];
                tshift = (lane == 0) ? ex : t;
            } else {
                tshift = INFF;             // R[-1][*] wall for strip 0
            }

            if (na == 0) {                 // predicated window (j >= 0 edge)
#pragma unroll
                for (int it = 0; it < 4; ++it) {
                    const int kk = 16 * it;
                    GITER1(0, true, kk)      GITER1(1, true, kk + 4)
                    GITER1(2, true, kk + 8)  GITER1(3, true, kk + 12)
                }
            } else {                       // hot loop
#pragma unroll 1
                for (int it = 0; it < 4; ++it) {
                    GITER1(0, false, 0) GITER1(1, false, 0)
                    GITER1(2, false, 0) GITER1(3, false, 0)
                }
            }

            if (strip < 7) {               // publish boundary block
                ring[strip][n & 1][lane] = tacc;
                if (lane == 0) extraS[strip][n & 1] = last_prev;
                last_prev = lane_bcast(tacc, 0);   // this window's last value
            }
        }
        __syncthreads();
    }
#undef GITER1
#undef CELL1

    // R[511][511]: strip 7 (wave 7), lane 63, diag 1022 (even bank)
    if (tid == 511) out[b] = rE;
}

// ---------------------------------------------------------------------------
extern "C" void kernel_launch(void* const* d_in, const int* in_sizes, int n_in,
                              void* d_out, int out_size, void* d_ws, size_t ws_size,
                              hipStream_t stream)
{
    const float* X = (const float*)d_in[0];
    const float* Y = (const float*)d_in[1];
    float* out = (float*)d_out;
    float* Dd  = (float*)d_ws;   // 32 * 256*512*4 floats = 64 MiB

    dim3 g1(S / 64, S / 64, BATCH);
    pairdist_kernel<<<g1, 256, 0, stream>>>(X, Y, Dd);

    softdtw_dp_stag8<<<BATCH, 512, 0, stream>>>(Dd, out);
}